// Round 5
// baseline (4485.811 us; speedup 1.0000x reference)
//
#include <hip/hip_runtime.h>

// HierarchicalGraphNet: N=100000 nodes, E=320000 edges, D=256, L=3, G=4096.
#define N_NODES 100000
#define N_EDGES 320000
#define N_GRAPH 4096
#define M_PAD   100096                   // N padded to multiple of 128
#define N_TILES 782                      // M_PAD / 128
#define LN_EPS  1e-5f
#define S_EL    ((size_t)M_PAD * 256)    // elements per full M x 256 plane
#define OENC_B  ((size_t)N_GRAPH * 1280 * 4)

typedef __attribute__((ext_vector_type(8))) short short8;   // 8 x bf16 MFMA operand
typedef __attribute__((ext_vector_type(4))) float f32x4;    // MFMA accumulator
typedef unsigned short u16;

__device__ __forceinline__ float bf2f(u16 u){
  return __uint_as_float(((unsigned)u) << 16);
}
__device__ __forceinline__ u16 f2bf(float f){   // RNE round
  unsigned u = __float_as_uint(f);
  return (u16)((u + 0x7FFFu + ((u >> 16) & 1u)) >> 16);
}
// external float tensor read: fp32 or bf16 per runtime flag
__device__ __forceinline__ float ldext(const void* p, long i, bool f32){
  return f32 ? ((const float*)p)[i] : bf2f(((const u16*)p)[i]);
}
// order-preserving float<->uint encoding for atomicMax-based segment_max
__device__ __forceinline__ unsigned enc_f(float f){
  unsigned u = __float_as_uint(f);
  return (u & 0x80000000u) ? ~u : (u | 0x80000000u);
}
__device__ __forceinline__ float dec_f(unsigned e){
  unsigned u = (e & 0x80000000u) ? (e & 0x7FFFFFFFu) : ~e;
  return __uint_as_float(u);
}
__device__ __forceinline__ float sigm(float x){ return 1.0f/(1.0f + __expf(-x)); }
__device__ __forceinline__ void ld4bf(const u16* p, float* o){
  ushort4 v = *(const ushort4*)p;
  o[0]=bf2f(v.x); o[1]=bf2f(v.y); o[2]=bf2f(v.z); o[3]=bf2f(v.w);
}

// ---- dtype detector ---------------------------------------------------------
// fp32 N(0,1) data: exponent field of u32 in [64,190] for ~all words.
// packed bf16 data: reinterpreted exponent lands in {0..7, 230..255}.
__global__ void k_detect(const unsigned* __restrict__ x32, int* __restrict__ flag){
  unsigned u = x32[threadIdx.x];            // 64 threads
  int ef = (int)((u >> 23) & 0xFFu);
  int ok = (ef >= 64 && ef <= 190) ? 1 : 0;
  #pragma unroll
  for (int o=1; o<64; o<<=1) ok += __shfl_xor(ok, o);
  if (threadIdx.x == 0) *flag = (ok >= 32) ? 1 : 0;
}

// ---- init kernels -----------------------------------------------------------
__global__ void k_h_init(const void* __restrict__ x, u16* __restrict__ h,
                         const int* __restrict__ dflag){
  const bool f32 = (*dflag != 0);
  int i = blockIdx.x*256 + threadIdx.x;     // 8 elements per thread
  size_t base = (size_t)i*8;
  int n = (int)(base >> 8);
  uint4 v = make_uint4(0,0,0,0);
  if (n < N_NODES){
    if (f32){
      const float* xf = (const float*)x + base;
      float4 a = *(const float4*)xf;
      float4 b = *(const float4*)(xf + 4);
      ushort4 lo = make_ushort4(f2bf(a.x),f2bf(a.y),f2bf(a.z),f2bf(a.w));
      ushort4 hi = make_ushort4(f2bf(b.x),f2bf(b.y),f2bf(b.z),f2bf(b.w));
      v.x = (unsigned)lo.x | ((unsigned)lo.y<<16);
      v.y = (unsigned)lo.z | ((unsigned)lo.w<<16);
      v.z = (unsigned)hi.x | ((unsigned)hi.y<<16);
      v.w = (unsigned)hi.z | ((unsigned)hi.w<<16);
    } else {
      v = *(const uint4*)((const u16*)x + base);
    }
  }
  *(uint4*)&h[base] = v;
}

__global__ void k_me_init(u16* __restrict__ m, u16* __restrict__ e){
  int i = blockIdx.x*256 + threadIdx.x;
  size_t base = (size_t)i*8;
  *(uint4*)&m[base] = make_uint4(0x3F803F80u,0x3F803F80u,0x3F803F80u,0x3F803F80u);
  *(uint4*)&e[base] = make_uint4(0,0,0,0);
}

// G = h (rows < N), 0 (pad rows)
__global__ void k_agg_init(const u16* __restrict__ h, u16* __restrict__ G){
  int i = blockIdx.x*256 + threadIdx.x;
  size_t base = (size_t)i*8;
  int n = (int)(base >> 8);
  uint4 v = make_uint4(0,0,0,0);
  if (n < N_NODES) v = *(const uint4*)&h[base];
  *(uint4*)&G[base] = v;
}

// G[dst] += h[src] over edges; 128 threads/edge, one packed u32 (2 bf16) each.
__global__ void k_edge_scatter(const unsigned* __restrict__ h32,
                               const int* __restrict__ ei,
                               unsigned* __restrict__ G32){
  int gid = blockIdx.x*256 + threadIdx.x;
  int e = gid >> 7;
  int j = gid & 127;
  int s = ei[e];
  int d = ei[N_EDGES + e];
  unsigned sv = h32[(size_t)s*128 + j];
  float vlo = bf2f((u16)(sv & 0xFFFFu));
  float vhi = bf2f((u16)(sv >> 16));
  unsigned* addr = &G32[(size_t)d*128 + j];
  unsigned old = *addr;
  while (true){
    unsigned assumed = old;
    u16 nl = f2bf(bf2f((u16)(assumed & 0xFFFFu)) + vlo);
    u16 nh = f2bf(bf2f((u16)(assumed >> 16)) + vhi);
    unsigned nv = (unsigned)nl | ((unsigned)nh << 16);
    old = atomicCAS(addr, assumed, nv);
    if (old == assumed) break;
  }
}

// ---- GEMM family ------------------------------------------------------------
// C[rows,256] = A[rows,K] @ B[256,K]^T + bias; A internal bf16, B/bias external
// (fp32 or bf16 per dflag). 128x128 tile, BK=32, 4 waves, 4x4 16x16x32 MFMA.
// LDS stride 40 (80 B = 20 banks -> 2-way conflicts only, free).
// MODE 0 LIN1 : relu -> Cout
// MODE 1 LIN2 : relu -> Cout
// MODE 2 HN   : none -> Cout             (h@Whn^T + bhh_n)
// MODE 3 RGATE: K=512 dual; sigm * aux   (r * hn)
// MODE 4 NGATE: tanh(acc + bias + aux)   (n)
// MODE 5 ZGATE: K=512 dual; (1-sigm)*aux + sigm*hglob  (hnew)
template<int MODE>
__global__ __launch_bounds__(256) void k_gemm(
    const u16* __restrict__ A1, const u16* __restrict__ A2,
    const void* __restrict__ Bv1, const void* __restrict__ Bv2,
    long bO1, long bO2,
    const void* __restrict__ biv1, const void* __restrict__ biv2,
    long biO1, long biO2,
    u16* __restrict__ Cout, const u16* __restrict__ aux,
    const u16* __restrict__ hglob, const int* __restrict__ dflag)
{
  constexpr int KTOT = (MODE==3 || MODE==5) ? 512 : 256;
  constexpr int BK = 32, LDSW = 40;
  const bool f32 = (*dflag != 0);
  __shared__ u16 As[128*LDSW];
  __shared__ u16 Bs[128*LDSW];
  const int rowBase = blockIdx.x * 128;
  const int colBase = blockIdx.y * 128;
  const int tid  = threadIdx.x;
  const int lane = tid & 63, wave = tid >> 6;
  const int wr = (wave >> 1) * 64, wc = (wave & 1) * 64;
  const int fr = lane & 15, quad = lane >> 4;

  f32x4 acc[4][4];
  {
    f32x4 z = {0.f,0.f,0.f,0.f};
    #pragma unroll
    for (int a=0;a<4;a++)
      #pragma unroll
      for (int b=0;b<4;b++) acc[a][b] = z;
  }

  for (int k0 = 0; k0 < KTOT; k0 += BK){
    #pragma unroll
    for (int t=0;t<2;t++){
      int id = tid + t*256;          // 512 tasks: 128 rows x 4 chunks of 8 elems
      int r  = id >> 2;
      int ch = (id & 3) * 8;
      const u16* Asrc = (KTOT==512 && k0 >= 256) ? A2 : A1;
      *(uint4*)&As[r*LDSW + ch] =
          *(const uint4*)&Asrc[(size_t)(rowBase + r)*256 + (k0 & 255) + ch];
      const void* Bv = (KTOT==512 && k0 >= 256) ? Bv2 : Bv1;
      long bO        = (KTOT==512 && k0 >= 256) ? bO2 : bO1;
      size_t bidx = (size_t)(colBase + r)*256 + (k0 & 255) + ch;
      if (f32){
        const float* Bf = (const float*)Bv + bO + bidx;
        float4 a = *(const float4*)Bf;
        float4 b = *(const float4*)(Bf + 4);
        *(ushort4*)&Bs[r*LDSW + ch]     = make_ushort4(f2bf(a.x),f2bf(a.y),f2bf(a.z),f2bf(a.w));
        *(ushort4*)&Bs[r*LDSW + ch + 4] = make_ushort4(f2bf(b.x),f2bf(b.y),f2bf(b.z),f2bf(b.w));
      } else {
        *(uint4*)&Bs[r*LDSW + ch] = *(const uint4*)((const u16*)Bv + bO + bidx);
      }
    }
    __syncthreads();
    short8 af[4], bfr[4];
    #pragma unroll
    for (int mi=0; mi<4; mi++)
      af[mi] = *(const short8*)&As[(wr + mi*16 + fr)*LDSW + quad*8];
    #pragma unroll
    for (int ni=0; ni<4; ni++)
      bfr[ni] = *(const short8*)&Bs[(wc + ni*16 + fr)*LDSW + quad*8];
    #pragma unroll
    for (int mi=0; mi<4; mi++)
      #pragma unroll
      for (int ni=0; ni<4; ni++)
        acc[mi][ni] = __builtin_amdgcn_mfma_f32_16x16x32_bf16(af[mi], bfr[ni], acc[mi][ni], 0, 0, 0);
    __syncthreads();
  }

  #pragma unroll
  for (int mi=0; mi<4; mi++){
    #pragma unroll
    for (int ni=0; ni<4; ni++){
      const int col = colBase + wc + ni*16 + fr;      // C/D: col = lane&15
      float bv = ldext(biv1, biO1 + col, f32);
      if constexpr (MODE==3 || MODE==5) bv += ldext(biv2, biO2 + col, f32);
      #pragma unroll
      for (int r4=0; r4<4; r4++){
        const int row = rowBase + wr + mi*16 + quad*4 + r4;   // row = quad*4+reg
        const size_t idx = (size_t)row*256 + col;
        float v = acc[mi][ni][r4] + bv;
        if constexpr (MODE==0 || MODE==1){
          v = fmaxf(v, 0.f);
        } else if constexpr (MODE==3){
          v = sigm(v) * bf2f(aux[idx]);                 // r * (h@Whn^T + bhh_n)
        } else if constexpr (MODE==4){
          v = tanhf(v + bf2f(aux[idx]));                // n
        } else if constexpr (MODE==5){
          float z = sigm(v);
          v = (1.f - z)*bf2f(aux[idx]) + z*bf2f(hglob[idx]);  // hnew
        }
        Cout[idx] = f2bf(v);
      }
    }
  }
}

// ---- BatchNorm over axis 0 (real N rows only) -------------------------------
__global__ void k_bn_stats(const u16* __restrict__ G, float* __restrict__ sums){
  int col = threadIdx.x;
  int n0 = blockIdx.x * 256;
  int n1 = min(N_NODES, n0 + 256);
  float s1 = 0.f, s2 = 0.f;
  for (int n = n0; n < n1; n++){
    float v = bf2f(G[(size_t)n*256 + col]);
    s1 += v; s2 += v*v;
  }
  unsafeAtomicAdd(&sums[col],       s1);
  unsafeAtomicAdd(&sums[256 + col], s2);
}

__global__ void k_bn_apply(u16* __restrict__ G,
                           const void* __restrict__ gam, const void* __restrict__ bet,
                           long gO, const float* __restrict__ sums,
                           const int* __restrict__ dflag){
  const bool f32 = (*dflag != 0);
  int i = blockIdx.x*256 + threadIdx.x;
  size_t base = (size_t)i*4;
  int col = (int)(base & 255);
  ushort4 v = *(const ushort4*)&G[base];
  float vv[4] = {bf2f(v.x), bf2f(v.y), bf2f(v.z), bf2f(v.w)};
  u16 o[4];
  #pragma unroll
  for (int j=0;j<4;j++){
    float mu  = sums[col+j] * (1.f/N_NODES);
    float var = sums[256+col+j] * (1.f/N_NODES) - mu*mu;
    float sc  = ldext(gam, gO+col+j, f32) * rsqrtf(fmaxf(var, 0.f) + LN_EPS);
    o[j] = f2bf((vv[j]-mu)*sc + ldext(bet, gO+col+j, f32));
  }
  *(ushort4*)&G[base] = make_ushort4(o[0], o[1], o[2], o[3]);
}

// ---- LayerNorm(hnew) + h/m/e update + segment_max atomics (per chunk) -------
__global__ __launch_bounds__(256) void k_fin(
    const u16* __restrict__ hn, u16* __restrict__ h,
    u16* __restrict__ mb, u16* __restrict__ eb,
    const void* __restrict__ lng, const void* __restrict__ lnb,
    const int* __restrict__ batch, unsigned* __restrict__ outenc,
    int layer, int r0, const int* __restrict__ dflag)
{
  const bool f32 = (*dflag != 0);
  const int wave = threadIdx.x >> 6, lane = threadIdx.x & 63;
  const int n  = blockIdx.x*4 + wave;        // local row
  const int d0 = lane*4;
  const size_t rb = (size_t)n*256 + d0;
  float hv[4], mv[4], ev[4];
  ld4bf(&hn[rb], hv);
  ld4bf(&mb[rb], mv);
  ld4bf(&eb[rb], ev);

  float s1 = 0.f, s2 = 0.f;
  #pragma unroll
  for (int j=0;j<4;j++){ s1 += hv[j]; s2 += hv[j]*hv[j]; }
  #pragma unroll
  for (int off=1; off<64; off<<=1){
    s1 += __shfl_xor(s1, off);
    s2 += __shfl_xor(s2, off);
  }
  const float mu   = s1 * (1.f/256.f);
  const float var  = s2 * (1.f/256.f) - mu*mu;
  const float rstd = rsqrtf(fmaxf(var, 0.f) + LN_EPS);

  float hl[4];
  #pragma unroll
  for (int j=0;j<4;j++){
    hl[j] = (hv[j]-mu)*rstd*ldext(lng, d0+j, f32) + ldext(lnb, d0+j, f32);
    mv[j] *= hl[j];
    ev[j] += hl[j];
  }
  *(ushort4*)&h[rb]  = make_ushort4(f2bf(hl[0]), f2bf(hl[1]), f2bf(hl[2]), f2bf(hl[3]));
  *(ushort4*)&mb[rb] = make_ushort4(f2bf(mv[0]), f2bf(mv[1]), f2bf(mv[2]), f2bf(mv[3]));
  *(ushort4*)&eb[rb] = make_ushort4(f2bf(ev[0]), f2bf(ev[1]), f2bf(ev[2]), f2bf(ev[3]));

  const int ng = r0 + n;
  if (ng < N_NODES){
    const int g = batch[ng];
    unsigned* o1 = &outenc[(size_t)g*1280 + layer*256 + d0];
    atomicMax(&o1[0], enc_f(hl[0])); atomicMax(&o1[1], enc_f(hl[1]));
    atomicMax(&o1[2], enc_f(hl[2])); atomicMax(&o1[3], enc_f(hl[3]));
    if (layer == 2){
      unsigned* o2 = &outenc[(size_t)g*1280 + 768  + d0];
      unsigned* o3 = &outenc[(size_t)g*1280 + 1024 + d0];
      atomicMax(&o2[0], enc_f(mv[0])); atomicMax(&o2[1], enc_f(mv[1]));
      atomicMax(&o2[2], enc_f(mv[2])); atomicMax(&o2[3], enc_f(mv[3]));
      atomicMax(&o3[0], enc_f(ev[0])); atomicMax(&o3[1], enc_f(ev[1]));
      atomicMax(&o3[2], enc_f(ev[2])); atomicMax(&o3[3], enc_f(ev[3]));
    }
  }
}

__global__ void k_decode(const unsigned* __restrict__ enc, void* __restrict__ out,
                         const int* __restrict__ dflag){
  const bool f32 = (*dflag != 0);
  int i = blockIdx.x*256 + threadIdx.x;
  unsigned u = enc[i];
  float f = (u == 0u) ? __uint_as_float(0xFF800000u) : dec_f(u);  // empty -> -inf
  if (f32) ((float*)out)[i] = f;
  else     ((u16*)out)[i]   = f2bf(f);
}

// ---- launcher ---------------------------------------------------------------
extern "C" void kernel_launch(void* const* d_in, const int* in_sizes, int n_in,
                              void* d_out, int out_size, void* d_ws, size_t ws_size,
                              hipStream_t stream)
{
  const void* x   = d_in[0];
  const void* l1w = d_in[1];  const void* l1b = d_in[2];
  const void* l2w = d_in[3];  const void* l2b = d_in[4];
  const void* bng = d_in[5];  const void* bnb = d_in[6];
  const void* wih = d_in[7];  const void* whh = d_in[8];
  const void* bih = d_in[9];  const void* bhh = d_in[10];
  const void* lng = d_in[11]; const void* lnb = d_in[12];
  const int* ei    = (const int*)d_in[13];
  const int* batch = (const int*)d_in[14];
  (void)in_sizes; (void)n_in; (void)out_size;

  const size_t PL = S_EL * 2;            // bf16 plane bytes (51.25 MB)
  char* p = (char*)d_ws; size_t off = 0;
  auto take = [&](size_t b){ void* q = p + off; off += (b + 255) & ~(size_t)255; return q; };
  u16*      h    = (u16*)take(PL);
  u16*      m    = (u16*)take(PL);
  u16*      e    = (u16*)take(PL);
  u16*      G    = (u16*)take(PL);       // agg -> g0 -> g
  unsigned* oenc = (unsigned*)take(OENC_B);
  float*    bns  = (float*)take(512*4);
  int*      dflg = (int*)take(256);
  // chunk scratch sized from the actual remaining workspace
  const size_t TILE_B = 128*256*2;       // one 128-row bf16 tile (64 KB)
  size_t rem = (ws_size > off + 2*TILE_B) ? (ws_size - off) : 2*TILE_B;
  int CT = (int)((rem/2) / TILE_B);      // tiles per chunk
  if (CT < 1) CT = 1;
  if (CT > N_TILES) CT = N_TILES;
  u16* S1 = (u16*)take((size_t)CT*TILE_B);
  u16* S2 = (u16*)take((size_t)CT*TILE_B);

  k_detect<<<1, 64, 0, stream>>>((const unsigned*)x, dflg);
  hipMemsetAsync(oenc, 0, OENC_B, stream);
  k_h_init <<<S_EL/8/256, 256, 0, stream>>>(x, h, dflg);
  k_me_init<<<S_EL/8/256, 256, 0, stream>>>(m, e);

  for (int l = 0; l < 3; l++){
    const long wo = (long)l*768*256;     // per-layer GRU weight element offset
    const long bo = (long)l*768;
    hipMemsetAsync(bns, 0, 512*4, stream);
    k_agg_init    <<<S_EL/8/256, 256, 0, stream>>>(h, G);
    k_edge_scatter<<<(N_EDGES*128)/256, 256, 0, stream>>>((const unsigned*)h, ei, (unsigned*)G);
    for (int t0 = 0; t0 < N_TILES; t0 += CT){
      const int ct = min(CT, N_TILES - t0);
      const size_t o2 = (size_t)t0*128*256;
      dim3 gr(ct, 2);
      k_gemm<0><<<gr, 256, 0, stream>>>(G + o2, nullptr, l1w, nullptr, (long)l*65536, 0,
                                        l1b, nullptr, (long)l*256, 0, S1, nullptr, nullptr, dflg);
      k_gemm<1><<<gr, 256, 0, stream>>>(S1, nullptr, l2w, nullptr, (long)l*65536, 0,
                                        l2b, nullptr, (long)l*256, 0, G + o2, nullptr, nullptr, dflg);
    }
    k_bn_stats<<<(N_NODES + 255)/256, 256, 0, stream>>>(G, bns);
    k_bn_apply<<<S_EL/4/256, 256, 0, stream>>>(G, bng, bnb, (long)l*256, bns, dflg);
    for (int t0 = 0; t0 < N_TILES; t0 += CT){
      const int ct = min(CT, N_TILES - t0);
      const size_t o2 = (size_t)t0*128*256;
      dim3 gr(ct, 2);
      // hn = h@Whn^T + bhh_n
      k_gemm<2><<<gr, 256, 0, stream>>>(h + o2, nullptr, whh, nullptr, wo + 512*256, 0,
                                        bhh, nullptr, bo + 512, 0, S1, nullptr, nullptr, dflg);
      // rhn = sigm([g|h]@[Wir|Whr]^T + bir + bhr) * hn
      k_gemm<3><<<gr, 256, 0, stream>>>(G + o2, h + o2, wih, whh, wo, wo,
                                        bih, bhh, bo, bo, S2, S1, nullptr, dflg);
      // n = tanh(g@Win^T + bin + rhn)
      k_gemm<4><<<gr, 256, 0, stream>>>(G + o2, nullptr, wih, nullptr, wo + 512*256, 0,
                                        bih, nullptr, bo + 512, 0, S1, S2, nullptr, dflg);
      // hnew = (1-z)*n + z*h
      k_gemm<5><<<gr, 256, 0, stream>>>(G + o2, h + o2, wih, whh, wo + 256*256, wo + 256*256,
                                        bih, bhh, bo + 256, bo + 256, S2, S1, h + o2, dflg);
      k_fin<<<ct*128/4, 256, 0, stream>>>(S2, h + o2, m + o2, e + o2,
                                          lng, lnb, batch, oenc, l, t0*128, dflg);
    }
  }
  k_decode<<<(N_GRAPH*1280)/256, 256, 0, stream>>>(oenc, d_out, dflg);
}

// Round 6
// 3370.056 us; speedup vs baseline: 1.3311x; 1.3311x over previous
//
#include <hip/hip_runtime.h>

// HierarchicalGraphNet: N=100000 nodes, E=320000 edges, D=256, L=3, G=4096.
#define N_NODES 100000
#define N_EDGES 320000
#define N_GRAPH 4096
#define M_PAD   100096                   // N padded to multiple of 128
#define N_TILES 782                      // M_PAD / 128
#define LN_EPS  1e-5f
#define S_EL    ((size_t)M_PAD * 256)    // elements per full M x 256 plane
#define OENC_B  ((size_t)N_GRAPH * 512 * 4)   // m|e encoded maxima only

typedef __attribute__((ext_vector_type(8))) short short8;   // 8 x bf16 MFMA operand
typedef __attribute__((ext_vector_type(4))) float f32x4;    // MFMA accumulator
typedef unsigned short u16;

__device__ __forceinline__ float bf2f(u16 u){
  return __uint_as_float(((unsigned)u) << 16);
}
__device__ __forceinline__ u16 f2bf(float f){   // RNE round
  unsigned u = __float_as_uint(f);
  return (u16)((u + 0x7FFFu + ((u >> 16) & 1u)) >> 16);
}
// external float tensor read: fp32 or bf16 per runtime flag
__device__ __forceinline__ float ldext(const void* p, long i, bool f32){
  return f32 ? ((const float*)p)[i] : bf2f(((const u16*)p)[i]);
}
// order-preserving float<->uint encoding for atomicMax-based segment_max
__device__ __forceinline__ unsigned enc_f(float f){
  unsigned u = __float_as_uint(f);
  return (u & 0x80000000u) ? ~u : (u | 0x80000000u);
}
__device__ __forceinline__ float dec_f(unsigned e){
  unsigned u = (e & 0x80000000u) ? (e & 0x7FFFFFFFu) : ~e;
  return __uint_as_float(u);
}
__device__ __forceinline__ float sigm(float x){ return 1.0f/(1.0f + __expf(-x)); }
__device__ __forceinline__ void ld4bf(const u16* p, float* o){
  ushort4 v = *(const ushort4*)p;
  o[0]=bf2f(v.x); o[1]=bf2f(v.y); o[2]=bf2f(v.z); o[3]=bf2f(v.w);
}

// ---- dtype detector ---------------------------------------------------------
__global__ void k_detect(const unsigned* __restrict__ x32, int* __restrict__ flag){
  unsigned u = x32[threadIdx.x];            // 64 threads
  int ef = (int)((u >> 23) & 0xFFu);
  int ok = (ef >= 64 && ef <= 190) ? 1 : 0;
  #pragma unroll
  for (int o=1; o<64; o<<=1) ok += __shfl_xor(ok, o);
  if (threadIdx.x == 0) *flag = (ok >= 32) ? 1 : 0;
}

// ---- init kernels -----------------------------------------------------------
__global__ void k_h_init(const void* __restrict__ x, u16* __restrict__ h,
                         const int* __restrict__ dflag){
  const bool f32 = (*dflag != 0);
  int i = blockIdx.x*256 + threadIdx.x;     // 8 elements per thread
  size_t base = (size_t)i*8;
  int n = (int)(base >> 8);
  uint4 v = make_uint4(0,0,0,0);
  if (n < N_NODES){
    if (f32){
      const float* xf = (const float*)x + base;
      float4 a = *(const float4*)xf;
      float4 b = *(const float4*)(xf + 4);
      ushort4 lo = make_ushort4(f2bf(a.x),f2bf(a.y),f2bf(a.z),f2bf(a.w));
      ushort4 hi = make_ushort4(f2bf(b.x),f2bf(b.y),f2bf(b.z),f2bf(b.w));
      v.x = (unsigned)lo.x | ((unsigned)lo.y<<16);
      v.y = (unsigned)lo.z | ((unsigned)lo.w<<16);
      v.z = (unsigned)hi.x | ((unsigned)hi.y<<16);
      v.w = (unsigned)hi.z | ((unsigned)hi.w<<16);
    } else {
      v = *(const uint4*)((const u16*)x + base);
    }
  }
  *(uint4*)&h[base] = v;
}

__global__ void k_me_init(u16* __restrict__ m, u16* __restrict__ e){
  int i = blockIdx.x*256 + threadIdx.x;
  size_t base = (size_t)i*8;
  *(uint4*)&m[base] = make_uint4(0x3F803F80u,0x3F803F80u,0x3F803F80u,0x3F803F80u);
  *(uint4*)&e[base] = make_uint4(0,0,0,0);
}

// G = h (rows < N), 0 (pad rows)
__global__ void k_agg_init(const u16* __restrict__ h, u16* __restrict__ G){
  int i = blockIdx.x*256 + threadIdx.x;
  size_t base = (size_t)i*8;
  int n = (int)(base >> 8);
  uint4 v = make_uint4(0,0,0,0);
  if (n < N_NODES) v = *(const uint4*)&h[base];
  *(uint4*)&G[base] = v;
}

// G[dst] += h[src] over edges; 128 threads/edge, one packed u32 (2 bf16) each.
__global__ void k_edge_scatter(const unsigned* __restrict__ h32,
                               const int* __restrict__ ei,
                               unsigned* __restrict__ G32){
  int gid = blockIdx.x*256 + threadIdx.x;
  int e = gid >> 7;
  int j = gid & 127;
  int s = ei[e];
  int d = ei[N_EDGES + e];
  unsigned sv = h32[(size_t)s*128 + j];
  float vlo = bf2f((u16)(sv & 0xFFFFu));
  float vhi = bf2f((u16)(sv >> 16));
  unsigned* addr = &G32[(size_t)d*128 + j];
  unsigned old = *addr;
  while (true){
    unsigned assumed = old;
    u16 nl = f2bf(bf2f((u16)(assumed & 0xFFFFu)) + vlo);
    u16 nh = f2bf(bf2f((u16)(assumed >> 16)) + vhi);
    unsigned nv = (unsigned)nl | ((unsigned)nh << 16);
    old = atomicCAS(addr, assumed, nv);
    if (old == assumed) break;
  }
}

// ---- GEMM family (unchanged from round 5) -----------------------------------
// MODE 0 LIN1 : relu -> Cout            MODE 1 LIN2 : relu -> Cout
// MODE 2 HN   : none -> Cout            MODE 3 RGATE: K=512 dual; sigm * aux
// MODE 4 NGATE: tanh(acc+bias+aux)      MODE 5 ZGATE: K=512 dual; (1-z)*aux+z*h
template<int MODE>
__global__ __launch_bounds__(256) void k_gemm(
    const u16* __restrict__ A1, const u16* __restrict__ A2,
    const void* __restrict__ Bv1, const void* __restrict__ Bv2,
    long bO1, long bO2,
    const void* __restrict__ biv1, const void* __restrict__ biv2,
    long biO1, long biO2,
    u16* __restrict__ Cout, const u16* __restrict__ aux,
    const u16* __restrict__ hglob, const int* __restrict__ dflag)
{
  constexpr int KTOT = (MODE==3 || MODE==5) ? 512 : 256;
  constexpr int BK = 32, LDSW = 40;
  const bool f32 = (*dflag != 0);
  __shared__ u16 As[128*LDSW];
  __shared__ u16 Bs[128*LDSW];
  const int rowBase = blockIdx.x * 128;
  const int colBase = blockIdx.y * 128;
  const int tid  = threadIdx.x;
  const int lane = tid & 63, wave = tid >> 6;
  const int wr = (wave >> 1) * 64, wc = (wave & 1) * 64;
  const int fr = lane & 15, quad = lane >> 4;

  f32x4 acc[4][4];
  {
    f32x4 z = {0.f,0.f,0.f,0.f};
    #pragma unroll
    for (int a=0;a<4;a++)
      #pragma unroll
      for (int b=0;b<4;b++) acc[a][b] = z;
  }

  for (int k0 = 0; k0 < KTOT; k0 += BK){
    #pragma unroll
    for (int t=0;t<2;t++){
      int id = tid + t*256;          // 512 tasks: 128 rows x 4 chunks of 8 elems
      int r  = id >> 2;
      int ch = (id & 3) * 8;
      const u16* Asrc = (KTOT==512 && k0 >= 256) ? A2 : A1;
      *(uint4*)&As[r*LDSW + ch] =
          *(const uint4*)&Asrc[(size_t)(rowBase + r)*256 + (k0 & 255) + ch];
      const void* Bv = (KTOT==512 && k0 >= 256) ? Bv2 : Bv1;
      long bO        = (KTOT==512 && k0 >= 256) ? bO2 : bO1;
      size_t bidx = (size_t)(colBase + r)*256 + (k0 & 255) + ch;
      if (f32){
        const float* Bf = (const float*)Bv + bO + bidx;
        float4 a = *(const float4*)Bf;
        float4 b = *(const float4*)(Bf + 4);
        *(ushort4*)&Bs[r*LDSW + ch]     = make_ushort4(f2bf(a.x),f2bf(a.y),f2bf(a.z),f2bf(a.w));
        *(ushort4*)&Bs[r*LDSW + ch + 4] = make_ushort4(f2bf(b.x),f2bf(b.y),f2bf(b.z),f2bf(b.w));
      } else {
        *(uint4*)&Bs[r*LDSW + ch] = *(const uint4*)((const u16*)Bv + bO + bidx);
      }
    }
    __syncthreads();
    short8 af[4], bfr[4];
    #pragma unroll
    for (int mi=0; mi<4; mi++)
      af[mi] = *(const short8*)&As[(wr + mi*16 + fr)*LDSW + quad*8];
    #pragma unroll
    for (int ni=0; ni<4; ni++)
      bfr[ni] = *(const short8*)&Bs[(wc + ni*16 + fr)*LDSW + quad*8];
    #pragma unroll
    for (int mi=0; mi<4; mi++)
      #pragma unroll
      for (int ni=0; ni<4; ni++)
        acc[mi][ni] = __builtin_amdgcn_mfma_f32_16x16x32_bf16(af[mi], bfr[ni], acc[mi][ni], 0, 0, 0);
    __syncthreads();
  }

  #pragma unroll
  for (int mi=0; mi<4; mi++){
    #pragma unroll
    for (int ni=0; ni<4; ni++){
      const int col = colBase + wc + ni*16 + fr;      // C/D: col = lane&15
      float bv = ldext(biv1, biO1 + col, f32);
      if constexpr (MODE==3 || MODE==5) bv += ldext(biv2, biO2 + col, f32);
      #pragma unroll
      for (int r4=0; r4<4; r4++){
        const int row = rowBase + wr + mi*16 + quad*4 + r4;   // row = quad*4+reg
        const size_t idx = (size_t)row*256 + col;
        float v = acc[mi][ni][r4] + bv;
        if constexpr (MODE==0 || MODE==1){
          v = fmaxf(v, 0.f);
        } else if constexpr (MODE==3){
          v = sigm(v) * bf2f(aux[idx]);                 // r * (h@Whn^T + bhh_n)
        } else if constexpr (MODE==4){
          v = tanhf(v + bf2f(aux[idx]));                // n
        } else if constexpr (MODE==5){
          float z = sigm(v);
          v = (1.f - z)*bf2f(aux[idx]) + z*bf2f(hglob[idx]);  // hnew
        }
        Cout[idx] = f2bf(v);
      }
    }
  }
}

// ---- BatchNorm over axis 0 (real N rows only) -------------------------------
__global__ void k_bn_stats(const u16* __restrict__ G, float* __restrict__ sums){
  int col = threadIdx.x;
  int n0 = blockIdx.x * 256;
  int n1 = min(N_NODES, n0 + 256);
  float s1 = 0.f, s2 = 0.f;
  for (int n = n0; n < n1; n++){
    float v = bf2f(G[(size_t)n*256 + col]);
    s1 += v; s2 += v*v;
  }
  unsafeAtomicAdd(&sums[col],       s1);
  unsafeAtomicAdd(&sums[256 + col], s2);
}

__global__ void k_bn_apply(u16* __restrict__ G,
                           const void* __restrict__ gam, const void* __restrict__ bet,
                           long gO, const float* __restrict__ sums,
                           const int* __restrict__ dflag){
  const bool f32 = (*dflag != 0);
  int i = blockIdx.x*256 + threadIdx.x;
  size_t base = (size_t)i*4;
  int col = (int)(base & 255);
  ushort4 v = *(const ushort4*)&G[base];
  float vv[4] = {bf2f(v.x), bf2f(v.y), bf2f(v.z), bf2f(v.w)};
  u16 o[4];
  #pragma unroll
  for (int j=0;j<4;j++){
    float mu  = sums[col+j] * (1.f/N_NODES);
    float var = sums[256+col+j] * (1.f/N_NODES) - mu*mu;
    float sc  = ldext(gam, gO+col+j, f32) * rsqrtf(fmaxf(var, 0.f) + LN_EPS);
    o[j] = f2bf((vv[j]-mu)*sc + ldext(bet, gO+col+j, f32));
  }
  *(ushort4*)&G[base] = make_ushort4(o[0], o[1], o[2], o[3]);
}

// ---- LayerNorm(hnew) + h/m/e update; layer2: m/e maxima via reduced atomics -
__global__ __launch_bounds__(256) void k_fin(
    const u16* __restrict__ hn, u16* __restrict__ h,
    u16* __restrict__ mb, u16* __restrict__ eb,
    const void* __restrict__ lng, const void* __restrict__ lnb,
    const int* __restrict__ batch, unsigned* __restrict__ outenc,
    int layer, int r0, const int* __restrict__ dflag)
{
  const bool f32 = (*dflag != 0);
  const int wave = threadIdx.x >> 6, lane = threadIdx.x & 63;
  const int n  = blockIdx.x*4 + wave;        // local row
  const int d0 = lane*4;
  const size_t rb = (size_t)n*256 + d0;
  float hv[4], mv[4], ev[4];
  ld4bf(&hn[rb], hv);
  ld4bf(&mb[rb], mv);
  ld4bf(&eb[rb], ev);

  float s1 = 0.f, s2 = 0.f;
  #pragma unroll
  for (int j=0;j<4;j++){ s1 += hv[j]; s2 += hv[j]*hv[j]; }
  #pragma unroll
  for (int off=1; off<64; off<<=1){
    s1 += __shfl_xor(s1, off);
    s2 += __shfl_xor(s2, off);
  }
  const float mu   = s1 * (1.f/256.f);
  const float var  = s2 * (1.f/256.f) - mu*mu;
  const float rstd = rsqrtf(fmaxf(var, 0.f) + LN_EPS);

  float hl[4];
  #pragma unroll
  for (int j=0;j<4;j++){
    hl[j] = (hv[j]-mu)*rstd*ldext(lng, d0+j, f32) + ldext(lnb, d0+j, f32);
    mv[j] *= hl[j];
    ev[j] += hl[j];
  }
  *(ushort4*)&h[rb]  = make_ushort4(f2bf(hl[0]), f2bf(hl[1]), f2bf(hl[2]), f2bf(hl[3]));
  if (layer != 2){                            // m/e planes dead after layer 2
    *(ushort4*)&mb[rb] = make_ushort4(f2bf(mv[0]), f2bf(mv[1]), f2bf(mv[2]), f2bf(mv[3]));
    *(ushort4*)&eb[rb] = make_ushort4(f2bf(ev[0]), f2bf(ev[1]), f2bf(ev[2]), f2bf(ev[3]));
  }

  if (layer == 2){
    // block covers 4 rows; pre-reduce m/e across rows when all 4 share a graph.
    __shared__ float redm[1024], rede[1024];
    __shared__ int bgs[4];
    const int ng = r0 + n;
    if (lane == 0) bgs[wave] = (ng < N_NODES) ? batch[ng] : -1;
    #pragma unroll
    for (int j=0;j<4;j++){ redm[wave*256 + d0 + j] = mv[j]; rede[wave*256 + d0 + j] = ev[j]; }
    __syncthreads();
    const bool uniform = (bgs[0] >= 0) && bgs[0]==bgs[1] && bgs[1]==bgs[2] && bgs[2]==bgs[3];
    if (uniform){
      const int c = threadIdx.x;              // 256 threads = 256 cols
      float mm = fmaxf(fmaxf(redm[c], redm[256+c]), fmaxf(redm[512+c], redm[768+c]));
      float me = fmaxf(fmaxf(rede[c], rede[256+c]), fmaxf(rede[512+c], rede[768+c]));
      unsigned* ob = &outenc[(size_t)bgs[0]*512];
      atomicMax(&ob[c],       enc_f(mm));
      atomicMax(&ob[256 + c], enc_f(me));
    } else {
      const int bg = (ng < N_NODES) ? batch[ng] : -1;
      if (bg >= 0){
        unsigned* ob = &outenc[(size_t)bg*512 + d0];
        atomicMax(&ob[0], enc_f(mv[0])); atomicMax(&ob[1], enc_f(mv[1]));
        atomicMax(&ob[2], enc_f(mv[2])); atomicMax(&ob[3], enc_f(mv[3]));
        atomicMax(&ob[256+0], enc_f(ev[0])); atomicMax(&ob[256+1], enc_f(ev[1]));
        atomicMax(&ob[256+2], enc_f(ev[2])); atomicMax(&ob[256+3], enc_f(ev[3]));
      }
    }
  }
}

// ---- atomic-free segment max over sorted batch: h plane -> out slice --------
// One wave per graph; lane covers 4 consecutive cols.
__global__ __launch_bounds__(256) void k_segmax(
    const u16* __restrict__ plane, void* __restrict__ out, long slice,
    const int* __restrict__ batch, const int* __restrict__ dflag)
{
  const bool f32 = (*dflag != 0);
  const int g = blockIdx.x*4 + (threadIdx.x >> 6);
  const int lane = threadIdx.x & 63;
  // lower_bound(g) and lower_bound(g+1) over sorted batch[0..N)
  int lo = 0, hi = N_NODES;
  while (lo < hi){ int mid = (lo + hi) >> 1; if (batch[mid] < g) lo = mid + 1; else hi = mid; }
  const int s = lo;
  hi = N_NODES;
  while (lo < hi){ int mid = (lo + hi) >> 1; if (batch[mid] < g + 1) lo = mid + 1; else hi = mid; }
  const int epos = lo;

  const float NINF = __uint_as_float(0xFF800000u);
  float a0=NINF, a1=NINF, a2=NINF, a3=NINF;
  for (int r = s; r < epos; r++){
    ushort4 v = *(const ushort4*)&plane[(size_t)r*256 + lane*4];
    a0 = fmaxf(a0, bf2f(v.x)); a1 = fmaxf(a1, bf2f(v.y));
    a2 = fmaxf(a2, bf2f(v.z)); a3 = fmaxf(a3, bf2f(v.w));
  }
  const long ob = (long)g*1280 + slice + lane*4;
  if (f32){
    float* o = (float*)out + ob;
    o[0]=a0; o[1]=a1; o[2]=a2; o[3]=a3;
  } else {
    *(ushort4*)((u16*)out + ob) = make_ushort4(f2bf(a0), f2bf(a1), f2bf(a2), f2bf(a3));
  }
}

// decode m/e maxima: oenc[g*512 + c] -> out[g*1280 + 768 + c]
__global__ void k_decode_me(const unsigned* __restrict__ enc, void* __restrict__ out,
                            const int* __restrict__ dflag){
  const bool f32 = (*dflag != 0);
  int i = blockIdx.x*256 + threadIdx.x;      // 4096*512
  int g = i >> 9, c = i & 511;
  unsigned u = enc[i];
  float f = (u == 0u) ? __uint_as_float(0xFF800000u) : dec_f(u);  // empty -> -inf
  long o = (long)g*1280 + 768 + c;
  if (f32) ((float*)out)[o] = f;
  else     ((u16*)out)[o]   = f2bf(f);
}

// ---- launcher ---------------------------------------------------------------
extern "C" void kernel_launch(void* const* d_in, const int* in_sizes, int n_in,
                              void* d_out, int out_size, void* d_ws, size_t ws_size,
                              hipStream_t stream)
{
  const void* x   = d_in[0];
  const void* l1w = d_in[1];  const void* l1b = d_in[2];
  const void* l2w = d_in[3];  const void* l2b = d_in[4];
  const void* bng = d_in[5];  const void* bnb = d_in[6];
  const void* wih = d_in[7];  const void* whh = d_in[8];
  const void* bih = d_in[9];  const void* bhh = d_in[10];
  const void* lng = d_in[11]; const void* lnb = d_in[12];
  const int* ei    = (const int*)d_in[13];
  const int* batch = (const int*)d_in[14];
  (void)in_sizes; (void)n_in; (void)out_size;

  const size_t PL = S_EL * 2;            // bf16 plane bytes (51.25 MB)
  char* p = (char*)d_ws; size_t off = 0;
  auto take = [&](size_t b){ void* q = p + off; off += (b + 255) & ~(size_t)255; return q; };
  u16*      h    = (u16*)take(PL);
  u16*      m    = (u16*)take(PL);
  u16*      e    = (u16*)take(PL);
  u16*      G    = (u16*)take(PL);       // agg -> g0 -> g
  unsigned* oenc = (unsigned*)take(OENC_B);
  float*    bns  = (float*)take(512*4);
  int*      dflg = (int*)take(256);
  // chunk scratch sized from the actual remaining workspace
  const size_t TILE_B = 128*256*2;       // one 128-row bf16 tile (64 KB)
  size_t rem = (ws_size > off + 2*TILE_B) ? (ws_size - off) : 2*TILE_B;
  int CT = (int)((rem/2) / TILE_B);      // tiles per chunk
  if (CT < 1) CT = 1;
  if (CT > N_TILES) CT = N_TILES;
  u16* S1 = (u16*)take((size_t)CT*TILE_B);
  u16* S2 = (u16*)take((size_t)CT*TILE_B);

  k_detect<<<1, 64, 0, stream>>>((const unsigned*)x, dflg);
  hipMemsetAsync(oenc, 0, OENC_B, stream);
  k_h_init <<<S_EL/8/256, 256, 0, stream>>>(x, h, dflg);
  k_me_init<<<S_EL/8/256, 256, 0, stream>>>(m, e);

  for (int l = 0; l < 3; l++){
    const long wo = (long)l*768*256;     // per-layer GRU weight element offset
    const long bo = (long)l*768;
    hipMemsetAsync(bns, 0, 512*4, stream);
    k_agg_init    <<<S_EL/8/256, 256, 0, stream>>>(h, G);
    k_edge_scatter<<<(N_EDGES*128)/256, 256, 0, stream>>>((const unsigned*)h, ei, (unsigned*)G);
    for (int t0 = 0; t0 < N_TILES; t0 += CT){
      const int ct = min(CT, N_TILES - t0);
      const size_t o2 = (size_t)t0*128*256;
      dim3 gr(ct, 2);
      k_gemm<0><<<gr, 256, 0, stream>>>(G + o2, nullptr, l1w, nullptr, (long)l*65536, 0,
                                        l1b, nullptr, (long)l*256, 0, S1, nullptr, nullptr, dflg);
      k_gemm<1><<<gr, 256, 0, stream>>>(S1, nullptr, l2w, nullptr, (long)l*65536, 0,
                                        l2b, nullptr, (long)l*256, 0, G + o2, nullptr, nullptr, dflg);
    }
    k_bn_stats<<<(N_NODES + 255)/256, 256, 0, stream>>>(G, bns);
    k_bn_apply<<<S_EL/4/256, 256, 0, stream>>>(G, bng, bnb, (long)l*256, bns, dflg);
    for (int t0 = 0; t0 < N_TILES; t0 += CT){
      const int ct = min(CT, N_TILES - t0);
      const size_t o2 = (size_t)t0*128*256;
      dim3 gr(ct, 2);
      // hn = h@Whn^T + bhh_n
      k_gemm<2><<<gr, 256, 0, stream>>>(h + o2, nullptr, whh, nullptr, wo + 512*256, 0,
                                        bhh, nullptr, bo + 512, 0, S1, nullptr, nullptr, dflg);
      // rhn = sigm([g|h]@[Wir|Whr]^T + bir + bhr) * hn
      k_gemm<3><<<gr, 256, 0, stream>>>(G + o2, h + o2, wih, whh, wo, wo,
                                        bih, bhh, bo, bo, S2, S1, nullptr, dflg);
      // n = tanh(g@Win^T + bin + rhn)
      k_gemm<4><<<gr, 256, 0, stream>>>(G + o2, nullptr, wih, nullptr, wo + 512*256, 0,
                                        bih, nullptr, bo + 512, 0, S1, S2, nullptr, dflg);
      // hnew = (1-z)*n + z*h
      k_gemm<5><<<gr, 256, 0, stream>>>(G + o2, h + o2, wih, whh, wo + 256*256, wo + 256*256,
                                        bih, bhh, bo + 256, bo + 256, S2, S1, h + o2, dflg);
      k_fin<<<ct*128/4, 256, 0, stream>>>(S2, h + o2, m + o2, e + o2,
                                          lng, lnb, batch, oenc, l, t0*128, dflg);
    }
    k_segmax<<<N_GRAPH/4, 256, 0, stream>>>(h, d_out, (long)l*256, batch, dflg);
  }
  k_decode_me<<<(N_GRAPH*512)/256, 256, 0, stream>>>(oenc, d_out, dflg);
}